// Round 1
// baseline (201.718 us; speedup 1.0000x reference)
//
#include <hip/hip_runtime.h>
#include <hip/hip_bf16.h>
#include <math.h>

// Shapes fixed by setup_inputs(): B=64, C=128, H=56, W=56.
// C is taken from in_sizes[1] (gamma), HW hard-coded (in_sizes can't split B vs H*W).
constexpr int HW = 56 * 56;   // 3136

// Round-to-nearest-even fp32 -> bf16 -> fp32, matching jnp astype(bfloat16).
__device__ __forceinline__ float qbf(float f) {
    unsigned u = __float_as_uint(f);
    u += 0x7fffu + ((u >> 16) & 1u);
    u &= 0xffff0000u;
    return __uint_as_float(u);
}

// ---------------- Kernel A: per-(channel, chunk) max / min / sum ----------------
__global__ __launch_bounds__(256) void stats_kernel(
    const float* __restrict__ x, const int* __restrict__ nch_p,
    int C, int n,  // n = B*H*W (elements per channel)
    float* __restrict__ ws_max, float* __restrict__ ws_min, float* __restrict__ ws_sum)
{
    const int nch = *nch_p;
    const int cs  = n / nch;        // chunk size (elements)
    const int P   = C * nch;        // total (c, chunk) pairs

    __shared__ float smax[4], smin[4], ssum[4];

    for (int p = blockIdx.x; p < P; p += gridDim.x) {
        const int c = p / nch;
        const int j = p - c * nch;

        float vmax = -INFINITY, vmin = INFINITY, vsum = 0.f;

        if ((cs & 3) == 0) {
            const int cs4 = cs >> 2;
            for (int t = threadIdx.x; t < cs4; t += blockDim.x) {
                const int f = j * cs + 4 * t;          // flat (B,H,W) index, f%4==0
                const int b = f / HW;                  // HW constexpr -> magic mul
                const int r = f - b * HW;              // r%4==0 since HW%4==0
                const float4 v = *reinterpret_cast<const float4*>(
                    x + ((size_t)b * C + c) * HW + r);
                const float a0 = qbf(v.x), a1 = qbf(v.y), a2 = qbf(v.z), a3 = qbf(v.w);
                vmax = fmaxf(vmax, fmaxf(fmaxf(a0, a1), fmaxf(a2, a3)));
                vmin = fminf(vmin, fminf(fminf(a0, a1), fminf(a2, a3)));
                vsum += (a0 + a1) + (a2 + a3);
            }
        } else {
            for (int t = threadIdx.x; t < cs; t += blockDim.x) {
                const int f = j * cs + t;
                const int b = f / HW;
                const int r = f - b * HW;
                const float a = qbf(x[((size_t)b * C + c) * HW + r]);
                vmax = fmaxf(vmax, a);
                vmin = fminf(vmin, a);
                vsum += a;
            }
        }

        // wave64 butterfly reduce
        #pragma unroll
        for (int off = 32; off > 0; off >>= 1) {
            vmax = fmaxf(vmax, __shfl_xor(vmax, off));
            vmin = fminf(vmin, __shfl_xor(vmin, off));
            vsum += __shfl_xor(vsum, off);
        }
        const int wave = threadIdx.x >> 6;
        if ((threadIdx.x & 63) == 0) { smax[wave] = vmax; smin[wave] = vmin; ssum[wave] = vsum; }
        __syncthreads();
        if (threadIdx.x == 0) {
            float m = smax[0], mi = smin[0], s = ssum[0];
            const int nw = blockDim.x >> 6;
            for (int w = 1; w < nw; ++w) {
                m = fmaxf(m, smax[w]); mi = fminf(mi, smin[w]); s += ssum[w];
            }
            ws_max[p] = m; ws_min[p] = mi; ws_sum[p] = s;
        }
        __syncthreads();  // protect smem reuse across grid-stride iterations
    }
}

// ---------------- Kernel B: per-channel avg & scale (reference quantization chain) ----------------
__global__ __launch_bounds__(256) void finalize_kernel(
    const float* __restrict__ ws_max, const float* __restrict__ ws_min,
    const float* __restrict__ ws_sum, const int* __restrict__ nch_p,
    int C, int n, float* __restrict__ avg_out, float* __restrict__ scale_out)
{
    const int c = blockIdx.x * blockDim.x + threadIdx.x;
    if (c >= C) return;
    const int nch = *nch_p;

    float smax = 0.f, smin = 0.f, stot = 0.f;
    for (int j = 0; j < nch; ++j) {
        smax += ws_max[c * nch + j];
        smin += ws_min[c * nch + j];
        stot += ws_sum[c * nch + j];
    }
    smax = qbf(smax);                                  // sum_max = _q(...)
    smin = qbf(smin);                                  // sum_min = _q(...)
    const float avg_max = qbf(smax / (float)nch);      // avg_max = _q(sum_max / num_chunks)
    const float avg_min = qbf(smin / (float)nch);
    const float total   = qbf(stot);                   // total = _q(sum)
    const float avg     = qbf(total / (float)n);       // avg = _q(total / n)

    const int cs = n / nch;
    const double sf_d = 1.0 / sqrt(2.0 * log((double)cs));   // numpy double, then f32
    const float scale_fix = (float)sf_d;
    const float scale = qbf(1.0f / ((avg_max - avg_min) * scale_fix + 1e-5f));

    avg_out[c]   = avg;
    scale_out[c] = scale;
}

// ---------------- Kernel C: elementwise normalize ----------------
__global__ __launch_bounds__(256) void norm_kernel(
    const float* __restrict__ x, const float* __restrict__ gamma,
    const float* __restrict__ beta, const float* __restrict__ avg,
    const float* __restrict__ scale, int C, long total, float* __restrict__ out)
{
    const long total4 = total >> 2;
    const long stride = (long)gridDim.x * blockDim.x;
    for (long i4 = (long)blockIdx.x * blockDim.x + threadIdx.x; i4 < total4; i4 += stride) {
        const long i = i4 << 2;
        const int  c = (int)((i / HW) % C);   // wave-uniform most of the time -> L1 broadcast
        const float a = avg[c], s = scale[c], g = qbf(gamma[c]), bt = beta[c];
        const float4 v = *reinterpret_cast<const float4*>(x + i);
        float4 o;
        o.x = qbf(qbf((qbf(v.x) - a) * s) * g + bt);
        o.y = qbf(qbf((qbf(v.y) - a) * s) * g + bt);
        o.z = qbf(qbf((qbf(v.z) - a) * s) * g + bt);
        o.w = qbf(qbf((qbf(v.w) - a) * s) * g + bt);
        *reinterpret_cast<float4*>(out + i) = o;
    }
    // scalar tail (total % 4), normally empty
    const long rem_start = total4 << 2;
    if (blockIdx.x == 0) {
        for (long i = rem_start + threadIdx.x; i < total; i += blockDim.x) {
            const int c = (int)((i / HW) % C);
            const float a = avg[c], s = scale[c], g = qbf(gamma[c]), bt = beta[c];
            out[i] = qbf(qbf((qbf(x[i]) - a) * s) * g + bt);
        }
    }
}

extern "C" void kernel_launch(void* const* d_in, const int* in_sizes, int n_in,
                              void* d_out, int out_size, void* d_ws, size_t ws_size,
                              hipStream_t stream) {
    const float* x     = (const float*)d_in[0];
    const float* gamma = (const float*)d_in[1];
    const float* beta  = (const float*)d_in[2];
    const int*   nch_p = (const int*)d_in[3];
    float* out = (float*)d_out;

    const int  C     = in_sizes[1];          // 128
    const long total = (long)in_sizes[0];    // B*C*H*W = 25,690,112
    const int  n     = (int)(total / C);     // per-channel elements = 200,704

    // Workspace layout (floats): [0,Pmax) max | [Pmax,2Pmax) min | [2Pmax,3Pmax) sum
    //                            | 3Pmax: avg[C] | 3Pmax+Cmax: scale[C]
    constexpr int Pmax = 4096, Cmax = 1024;
    float* ws_f   = (float*)d_ws;
    float* ws_max = ws_f;
    float* ws_min = ws_f + Pmax;
    float* ws_sum = ws_f + 2 * Pmax;
    float* avg    = ws_f + 3 * Pmax;
    float* scale  = ws_f + 3 * Pmax + Cmax;

    stats_kernel<<<1024, 256, 0, stream>>>(x, nch_p, C, n, ws_max, ws_min, ws_sum);
    finalize_kernel<<<(C + 255) / 256, 256, 0, stream>>>(ws_max, ws_min, ws_sum,
                                                         nch_p, C, n, avg, scale);
    norm_kernel<<<2048, 256, 0, stream>>>(x, gamma, beta, avg, scale, C, total, out);
}